// Round 10
// baseline (131.743 us; speedup 1.0000x reference)
//
#include <hip/hip_runtime.h>

#define DEV_INLINE static __device__ __forceinline__

typedef __attribute__((ext_vector_type(8))) short bf16x8;
typedef __attribute__((ext_vector_type(4))) float f32x4;
typedef __attribute__((ext_vector_type(16))) float f32x16;

DEV_INLINE unsigned short f2bf(float f) {
  union { float f; unsigned int u; } v; v.f = f;
  unsigned int u = v.u;
  u += 0x7FFFu + ((u >> 16) & 1u);   // RNE
  return (unsigned short)(u >> 16);
}
DEV_INLINE float bf2f(unsigned short h) {
  union { unsigned int u; float f; } v; v.u = ((unsigned int)h) << 16; return v.f;
}

// ---------------- fp32 -> bf16 conversion ----------------
__global__ __launch_bounds__(256) void cvt_f32_bf16(const float* __restrict__ in,
                                                    unsigned short* __restrict__ out, int n4) {
  int i = blockIdx.x * 256 + threadIdx.x;
  if (i >= n4) return;
  float4 v = reinterpret_cast<const float4*>(in)[i];
  ushort4 o;
  o.x = f2bf(v.x); o.y = f2bf(v.y); o.z = f2bf(v.z); o.w = f2bf(v.w);
  reinterpret_cast<ushort4*>(out)[i] = o;
}

// ---------------- GEMM: C[M,N] = A[M,768] * B[N,768]^T (+bias) ----------------
// 3-buffer deep pipeline (kept from r9 — it left the top-5): counted vmcnt +
// raw s_barrier, BK=32, global_load_lds width=16, XOR involution.
// MODE 0: qkv scatter; q scaled by log2e, k scaled by 0.125
// MODE 1: output projection, fp32 out [4096][768]
template <int MODE>
__global__ __launch_bounds__(256) void gemm_bf16(const unsigned short* __restrict__ A,
                                                 const unsigned short* __restrict__ Bw,
                                                 const float* __restrict__ bias,
                                                 float* __restrict__ outF,
                                                 unsigned short* __restrict__ qo,
                                                 unsigned short* __restrict__ ko,
                                                 unsigned short* __restrict__ vo) {
  __shared__ unsigned short As[3][128 * 32];
  __shared__ unsigned short Bs[3][128 * 32];

  const int tid = threadIdx.x;
  const int lane = tid & 63;
  const int wv = tid >> 6;
  const int wrow = (wv >> 1) * 64;
  const int wcol = (wv & 1) * 64;
  const int m0 = blockIdx.y * 128;
  const int n0 = blockIdx.x * 128;
  const int l15 = lane & 15;
  const int lg = lane >> 4;

  const int srow = lane >> 2;                  // 0..15 within a 16-row chunk
  const int seg  = (lane & 3) ^ (srow & 3);    // pre-swizzled global k-segment

  f32x4 acc[4][4];
#pragma unroll
  for (int i = 0; i < 4; ++i)
#pragma unroll
    for (int j = 0; j < 4; ++j) acc[i][j] = (f32x4){0.f, 0.f, 0.f, 0.f};

#define GSTAGE(KT, B)                                                                        \
  do {                                                                                       \
    _Pragma("unroll") for (int pp = 0; pp < 2; ++pp) {                                       \
      int p = wv * 2 + pp;                     /* 16-row chunk, wave-uniform */              \
      int row = p * 16 + srow;                                                               \
      const unsigned short* ga = &A[(m0 + row) * 768 + (KT) * 32 + seg * 8];                 \
      __builtin_amdgcn_global_load_lds(                                                      \
          (const __attribute__((address_space(1))) unsigned int*)ga,                         \
          (__attribute__((address_space(3))) unsigned int*)&As[B][p * 512], 16, 0, 0);       \
      const unsigned short* gb = &Bw[(n0 + row) * 768 + (KT) * 32 + seg * 8];                \
      __builtin_amdgcn_global_load_lds(                                                      \
          (const __attribute__((address_space(1))) unsigned int*)gb,                         \
          (__attribute__((address_space(3))) unsigned int*)&Bs[B][p * 512], 16, 0, 0);       \
    }                                                                                        \
  } while (0)

  GSTAGE(0, 0);
  GSTAGE(1, 1);

  const int soff = (lg ^ (l15 & 3)) * 8;       // read-side of the involution

#pragma unroll
  for (int kt = 0; kt < 24; ++kt) {
    const int b = kt % 3;
    // wait for tile kt only; tile kt+1's 4 loads stay in flight across the barrier
    if (kt < 23) asm volatile("s_waitcnt vmcnt(4)" ::: "memory");
    else         asm volatile("s_waitcnt vmcnt(0)" ::: "memory");
    __builtin_amdgcn_s_barrier();
    asm volatile("" ::: "memory");
    if (kt < 22) GSTAGE(kt + 2, (kt + 2) % 3);  // into buffer freed at kt-1

    bf16x8 aF[4], bF[4];
#pragma unroll
    for (int i = 0; i < 4; ++i)
      aF[i] = *reinterpret_cast<const bf16x8*>(&As[b][(wrow + i * 16 + l15) * 32 + soff]);
#pragma unroll
    for (int j = 0; j < 4; ++j)
      bF[j] = *reinterpret_cast<const bf16x8*>(&Bs[b][(wcol + j * 16 + l15) * 32 + soff]);
#pragma unroll
    for (int i = 0; i < 4; ++i)
#pragma unroll
      for (int j = 0; j < 4; ++j)
        acc[i][j] = __builtin_amdgcn_mfma_f32_16x16x32_bf16(aF[i], bF[j], acc[i][j], 0, 0, 0);
  }
#undef GSTAGE

#pragma unroll
  for (int i = 0; i < 4; ++i) {
#pragma unroll
    for (int j = 0; j < 4; ++j) {
#pragma unroll
      for (int r = 0; r < 4; ++r) {
        int row = m0 + wrow + i * 16 + (lane >> 4) * 4 + r;
        int col = n0 + wcol + j * 16 + l15;
        float val = acc[i][j][r] + bias[col];
        if (MODE == 0) {
          int t = col / 768;
          int rem = col - t * 768;
          int head = rem >> 6;
          int c = rem & 63;
          int bb = row >> 10;
          int n = row & 1023;
          if (t == 0) val *= 1.44269504f; // fold log2e into Q (exp2-domain softmax)
          if (t == 1) val *= 0.125f;      // fold q-scale into K
          unsigned short* dst = (t == 0) ? qo : (t == 1) ? ko : vo;
          dst[((bb * 12 + head) * 1024 + n) * 64 + c] = f2bf(val);
        } else {
          outF[row * 768 + col] = val;
        }
      }
    }
  }
}

// ---------------- V transpose: [48][1024][64] -> [48][64][1024] ----------------
__global__ __launch_bounds__(256) void vtrans(const unsigned short* __restrict__ vb,
                                              unsigned short* __restrict__ vt) {
  __shared__ unsigned short t[64][72];
  const int n0 = blockIdx.x * 64;
  const int bh = blockIdx.y;
  const int tid = threadIdx.x;
#pragma unroll
  for (int i = 0; i < 4; ++i) {
    int s = tid + i * 256;
    int row = s >> 4, c4 = (s & 15) * 4;
    *reinterpret_cast<ushort4*>(&t[row][c4]) =
        *reinterpret_cast<const ushort4*>(&vb[(bh * 1024 + n0 + row) * 64 + c4]);
  }
  __syncthreads();
#pragma unroll
  for (int i = 0; i < 4; ++i) {
    int s = tid + i * 256;
    int d = s >> 4, n4 = (s & 15) * 4;
    ushort4 o;
    o.x = t[n4 + 0][d]; o.y = t[n4 + 1][d]; o.z = t[n4 + 2][d]; o.w = t[n4 + 3][d];
    *reinterpret_cast<ushort4*>(&vt[(bh * 64 + d) * 1024 + n0 + n4]) = o;
  }
}

// ---------------- rel-pos via 16x16x32 MFMA (gemm-verified conventions) ----------------
// Input q is already scaled by log2e -> relh/relwb come out in log2 units.
DEV_INLINE f32x4 mfma16(bf16x8 a, bf16x8 b, f32x4 c) {
  return __builtin_amdgcn_mfma_f32_16x16x32_bf16(a, b, c, 0, 0, 0);
}

__global__ __launch_bounds__(64) void rel_mfma16(const unsigned short* __restrict__ q,
                                                 const float* __restrict__ rph,
                                                 const float* __restrict__ rpw,
                                                 unsigned short* __restrict__ relwb,
                                                 float* __restrict__ relh) {
  __shared__ unsigned short qs[32 * 72];
  __shared__ unsigned short rhh[32 * 72], rhl[32 * 72];
  __shared__ unsigned short rwh[64 * 72], rwl[64 * 72];
  __shared__ float relh_s[32 * 36];
  __shared__ unsigned short relw_s[32 * 40];

  const int lane = threadIdx.x;
  const int l15 = lane & 15;
  const int lg = lane >> 4;
  const int qh = blockIdx.x;   // 0..31
  const int bh = blockIdx.y;   // 0..47

#pragma unroll
  for (int it = 0; it < 4; ++it) {
    int s = lane + it * 64;
    int row = s >> 3, ch = s & 7;
    *reinterpret_cast<int4*>(&qs[row * 72 + ch * 8]) =
        *reinterpret_cast<const int4*>(&q[(bh * 1024 + qh * 32 + row) * 64 + ch * 8]);
  }
#pragma unroll
  for (int it = 0; it < 8; ++it) {
    int s = lane + it * 64;
    int row = s >> 4, c4 = (s & 15) * 4;
    float4 v = *reinterpret_cast<const float4*>(&rph[(qh + row) * 64 + c4]);
    ushort4 h, l;
    h.x = f2bf(v.x); l.x = f2bf(v.x - bf2f(h.x));
    h.y = f2bf(v.y); l.y = f2bf(v.y - bf2f(h.y));
    h.z = f2bf(v.z); l.z = f2bf(v.z - bf2f(h.z));
    h.w = f2bf(v.w); l.w = f2bf(v.w - bf2f(h.w));
    *reinterpret_cast<ushort4*>(&rhh[row * 72 + c4]) = h;
    *reinterpret_cast<ushort4*>(&rhl[row * 72 + c4]) = l;
  }
#pragma unroll
  for (int it = 0; it < 16; ++it) {
    int s = lane + it * 64;
    int row = s >> 4, c4 = (s & 15) * 4;
    float4 v = (float4){0.f, 0.f, 0.f, 0.f};
    if (row < 63) v = *reinterpret_cast<const float4*>(&rpw[row * 64 + c4]);
    ushort4 h, l;
    h.x = f2bf(v.x); l.x = f2bf(v.x - bf2f(h.x));
    h.y = f2bf(v.y); l.y = f2bf(v.y - bf2f(h.y));
    h.z = f2bf(v.z); l.z = f2bf(v.z - bf2f(h.z));
    h.w = f2bf(v.w); l.w = f2bf(v.w - bf2f(h.w));
    *reinterpret_cast<ushort4*>(&rwh[row * 72 + c4]) = h;
    *reinterpret_cast<ushort4*>(&rwl[row * 72 + c4]) = l;
  }
  __syncthreads();

  const int k0 = lg * 8, k1 = 32 + lg * 8;
  bf16x8 fq[2][2], fhh[2][2], fhl[2][2], fwh[4][2], fwl[4][2];
#pragma unroll
  for (int t = 0; t < 2; ++t) {
    fq[t][0]  = *reinterpret_cast<const bf16x8*>(&qs[(t * 16 + l15) * 72 + k0]);
    fq[t][1]  = *reinterpret_cast<const bf16x8*>(&qs[(t * 16 + l15) * 72 + k1]);
    fhh[t][0] = *reinterpret_cast<const bf16x8*>(&rhh[(t * 16 + l15) * 72 + k0]);
    fhh[t][1] = *reinterpret_cast<const bf16x8*>(&rhh[(t * 16 + l15) * 72 + k1]);
    fhl[t][0] = *reinterpret_cast<const bf16x8*>(&rhl[(t * 16 + l15) * 72 + k0]);
    fhl[t][1] = *reinterpret_cast<const bf16x8*>(&rhl[(t * 16 + l15) * 72 + k1]);
  }
#pragma unroll
  for (int t = 0; t < 4; ++t) {
    fwh[t][0] = *reinterpret_cast<const bf16x8*>(&rwh[(t * 16 + l15) * 72 + k0]);
    fwh[t][1] = *reinterpret_cast<const bf16x8*>(&rwh[(t * 16 + l15) * 72 + k1]);
    fwl[t][0] = *reinterpret_cast<const bf16x8*>(&rwl[(t * 16 + l15) * 72 + k0]);
    fwl[t][1] = *reinterpret_cast<const bf16x8*>(&rwl[(t * 16 + l15) * 72 + k1]);
  }

  f32x4 ah[2][2];
#pragma unroll
  for (int i = 0; i < 2; ++i)
#pragma unroll
    for (int jj = 0; jj < 2; ++jj) {
      f32x4 a = (f32x4){0.f, 0.f, 0.f, 0.f};
      a = mfma16(fhh[i][0], fq[jj][0], a);
      a = mfma16(fhh[i][1], fq[jj][1], a);
      a = mfma16(fhl[i][0], fq[jj][0], a);
      a = mfma16(fhl[i][1], fq[jj][1], a);
      ah[i][jj] = a;
    }
  f32x4 aw[2][4];
#pragma unroll
  for (int i = 0; i < 2; ++i)
#pragma unroll
    for (int jj = 0; jj < 4; ++jj) {
      f32x4 a = (f32x4){0.f, 0.f, 0.f, 0.f};
      a = mfma16(fq[i][0], fwh[jj][0], a);
      a = mfma16(fq[i][1], fwh[jj][1], a);
      a = mfma16(fq[i][0], fwl[jj][0], a);
      a = mfma16(fq[i][1], fwl[jj][1], a);
      aw[i][jj] = a;
    }

#pragma unroll
  for (int i = 0; i < 2; ++i)
#pragma unroll
    for (int jj = 0; jj < 2; ++jj)
#pragma unroll
      for (int r = 0; r < 4; ++r) {
        int t = i * 16 + lg * 4 + r;
        int qw = jj * 16 + l15;
        relh_s[qw * 36 + 31 - t] = ah[i][jj][r];
      }
#pragma unroll
  for (int i = 0; i < 2; ++i)
#pragma unroll
    for (int jj = 0; jj < 4; ++jj)
#pragma unroll
      for (int r = 0; r < 4; ++r) {
        int qw = i * 16 + lg * 4 + r;
        int d = jj * 16 + l15;
        int kw = qw + 31 - d;
        if (kw >= 0 && kw < 32) relw_s[qw * 40 + kw] = f2bf(aw[i][jj][r]);
      }
  __syncthreads();

#pragma unroll
  for (int it = 0; it < 4; ++it) {
    int s = lane + it * 64;
    int row = s >> 3, c4 = (s & 7) * 4;
    *reinterpret_cast<float4*>(&relh[(bh * 1024 + qh * 32 + row) * 32 + c4]) =
        *reinterpret_cast<const float4*>(&relh_s[row * 36 + c4]);
  }
#pragma unroll
  for (int it = 0; it < 2; ++it) {
    int s = lane + it * 64;
    int row = s >> 2, ch = s & 3;
    *reinterpret_cast<int4*>(&relwb[(bh * 1024 + qh * 32 + row) * 32 + ch * 8]) =
        *reinterpret_cast<const int4*>(&relw_s[row * 40 + ch * 8]);
  }
}

// ---------------- flash attention, swapped-QK^T 32x32, exp2 domain ----------------
// No LDS, no barriers (m169: K/V is L2-resident). One wave per block, grid 1536.
// K frags reloaded into dead regs after QK^T issues; V frags loaded at loop top.
DEV_INLINE f32x16 mfma32(bf16x8 a, bf16x8 b, f32x16 c) {
  return __builtin_amdgcn_mfma_f32_32x32x16_bf16(a, b, c, 0, 0, 0);
}

DEV_INLINE bf16x8 make_pa(const float* p) {
  unsigned int W0, W1, W2, W3;
  asm("v_cvt_pk_bf16_f32 %0, %1, %2" : "=v"(W0) : "v"(p[0]), "v"(p[1]));
  asm("v_cvt_pk_bf16_f32 %0, %1, %2" : "=v"(W1) : "v"(p[2]), "v"(p[3]));
  asm("v_cvt_pk_bf16_f32 %0, %1, %2" : "=v"(W2) : "v"(p[4]), "v"(p[5]));
  asm("v_cvt_pk_bf16_f32 %0, %1, %2" : "=v"(W3) : "v"(p[6]), "v"(p[7]));
  asm("v_permlane32_swap_b32 %0, %1" : "+v"(W0), "+v"(W2));
  asm("v_permlane32_swap_b32 %0, %1" : "+v"(W1), "+v"(W3));
  union { unsigned int w[4]; bf16x8 v; } u;
  u.w[0] = W0; u.w[1] = W1; u.w[2] = W2; u.w[3] = W3;
  return u.v;
}

__global__ __launch_bounds__(64) void attn2(const unsigned short* __restrict__ kg,
                                            const unsigned short* __restrict__ vtg,
                                            const unsigned short* __restrict__ qg,
                                            const unsigned short* __restrict__ relwb,
                                            const float* __restrict__ relh,
                                            unsigned short* __restrict__ ao) {
  const int lane = threadIdx.x;
  const int l31 = lane & 31;
  const int hi = lane >> 5;

  const int bid = blockIdx.x;
  const int swz = (bid & 7) * 192 + (bid >> 3);  // XCD-chunked: 1536 = 8 x 192
  const int bh = swz >> 5;
  const int qt = swz & 31;
  const int q0 = qt * 32;

  bf16x8 qf[6];
  {
    const unsigned short* qrow = &qg[(bh * 1024 + q0 + l31) * 64 + hi * 8];
#pragma unroll
    for (int c = 0; c < 4; ++c)
      qf[c] = *reinterpret_cast<const bf16x8*>(&qrow[c * 16]);
    const unsigned short* wrow = &relwb[(bh * 1024 + q0 + l31) * 32 + hi * 8];
    qf[4] = *reinterpret_cast<const bf16x8*>(&wrow[0]);
    qf[5] = *reinterpret_cast<const bf16x8*>(&wrow[16]);
  }

  // one-hot relw A-frags
  bf16x8 ohf0, ohf1;
  {
    int t0 = l31 - 8 * hi;
    int t1 = l31 - 16 - 8 * hi;
    union { unsigned int w[4]; bf16x8 v; } u0, u1;
#pragma unroll
    for (int w = 0; w < 4; ++w) {
      u0.w[w] = (t0 >= 0 && (t0 >> 1) == w) ? ((t0 & 1) ? 0x3F800000u : 0x3F80u) : 0u;
      u1.w[w] = (t1 >= 0 && (t1 >> 1) == w) ? ((t1 & 1) ? 0x3F800000u : 0x3F80u) : 0u;
    }
    ohf0 = u0.v; ohf1 = u1.v;
  }

  f32x16 O0, O1;
#pragma unroll
  for (int r = 0; r < 16; ++r) { O0[r] = 0.f; O1[r] = 0.f; }
  float m_r = -3.0e38f, l_r = 0.f;

  // direct-global fragment offsets (elements)
  const unsigned short* kbase = kg + (size_t)bh * 1024 * 64;
  const unsigned short* vbase = vtg + (size_t)bh * 64 * 1024;
  const int koffA = l31 * 64 + hi * 8;
  const int koffB = (32 + l31) * 64 + hi * 8;
  const int voffA = l31 * 1024 + hi * 8;
  const int voffB = (32 + l31) * 1024 + hi * 8;

  bf16x8 kf[4][2];
#pragma unroll
  for (int c = 0; c < 4; ++c) {
    kf[c][0] = *reinterpret_cast<const bf16x8*>(&kbase[koffA + c * 16]);
    kf[c][1] = *reinterpret_cast<const bf16x8*>(&kbase[koffB + c * 16]);
  }

  const float* rhrow = &relh[(bh * 1024 + q0 + l31) * 32];
  float2 bhv = *reinterpret_cast<const float2*>(&rhrow[0]);

  for (int kt = 0; kt < 16; ++kt) {
    // V(kt) loads at top — hidden under QK^T + softmax
    const unsigned short* vb = vbase + kt * 64;
    bf16x8 vf[4][2];
#pragma unroll
    for (int c = 0; c < 4; ++c) {
      vf[c][0] = *reinterpret_cast<const bf16x8*>(&vb[voffA + c * 16]);
      vf[c][1] = *reinterpret_cast<const bf16x8*>(&vb[voffB + c * 16]);
    }

    float2 bhv_next = bhv;
    if (kt < 15) bhv_next = *reinterpret_cast<const float2*>(&rhrow[2 * (kt + 1)]);
    float bh0 = bhv.x, bh1 = bhv.y;

    f32x16 s0, s1;
#pragma unroll
    for (int r = 0; r < 16; ++r) { s0[r] = 0.f; s1[r] = 0.f; }
    __builtin_amdgcn_s_setprio(1);
#pragma unroll
    for (int c = 0; c < 4; ++c) {
      s0 = mfma32(kf[c][0], qf[c], s0);
      s1 = mfma32(kf[c][1], qf[c], s1);
    }
    s0 = mfma32(ohf0, qf[4], s0);
    s0 = mfma32(ohf1, qf[5], s0);
    s1 = mfma32(ohf0, qf[4], s1);
    s1 = mfma32(ohf1, qf[5], s1);
    __builtin_amdgcn_s_setprio(0);

    // K(kt+1) into the now-dead kf regs — ~softmax+PV of time to land
    {
      int ktn = (kt < 15) ? kt + 1 : 15;
      const unsigned short* kb = kbase + ktn * 64 * 64;
#pragma unroll
      for (int c = 0; c < 4; ++c) {
        kf[c][0] = *reinterpret_cast<const bf16x8*>(&kb[koffA + c * 16]);
        kf[c][1] = *reinterpret_cast<const bf16x8*>(&kb[koffB + c * 16]);
      }
    }

    float pm0 = s0[0], pm1 = s1[0];
#pragma unroll
    for (int r = 1; r < 16; ++r) { pm0 = fmaxf(pm0, s0[r]); pm1 = fmaxf(pm1, s1[r]); }
    float pmax = fmaxf(pm0 + bh0, pm1 + bh1);
    pmax = fmaxf(pmax, __shfl_xor(pmax, 32));

    if (!__all(pmax <= m_r + 11.5f)) {     // defer-max (log2 units): rescale is rare
      float mnew = fmaxf(m_r, pmax);
      float corr = __builtin_amdgcn_exp2f(m_r - mnew);
      m_r = mnew;
      l_r *= corr;
#pragma unroll
      for (int r = 0; r < 16; ++r) {
        int cr = ((r & 3) + 8 * (r >> 2) + 4 * hi) << 2;
        float c2 = __int_as_float(__builtin_amdgcn_ds_bpermute(cr, __float_as_int(corr)));
        O0[r] *= c2;
        O1[r] *= c2;
      }
    }

    float mb0 = m_r - bh0, mb1 = m_r - bh1;
    float p0[16], p1[16];
    float ps = 0.f;
#pragma unroll
    for (int r = 0; r < 16; ++r) { p0[r] = __builtin_amdgcn_exp2f(s0[r] - mb0); ps += p0[r]; }
#pragma unroll
    for (int r = 0; r < 16; ++r) { p1[r] = __builtin_amdgcn_exp2f(s1[r] - mb1); ps += p1[r]; }
    ps += __shfl_xor(ps, 32);
    l_r += ps;

    bf16x8 pa0 = make_pa(p0 + 0);
    bf16x8 pa1 = make_pa(p0 + 8);
    bf16x8 pa2 = make_pa(p1 + 0);
    bf16x8 pa3 = make_pa(p1 + 8);

    __builtin_amdgcn_s_setprio(1);
#pragma unroll
    for (int c = 0; c < 4; ++c) {
      bf16x8 pac = (c == 0) ? pa0 : (c == 1) ? pa1 : (c == 2) ? pa2 : pa3;
      O0 = mfma32(pac, vf[c][0], O0);
      O1 = mfma32(pac, vf[c][1], O1);
    }
    __builtin_amdgcn_s_setprio(0);

    bhv = bhv_next;
  }

  float invl = 1.f / l_r;
  const int bb = bh / 12, head = bh % 12;
#pragma unroll
  for (int r = 0; r < 16; ++r) {
    int crow = (r & 3) + 8 * (r >> 2) + 4 * hi;
    float il = __int_as_float(__builtin_amdgcn_ds_bpermute(crow << 2, __float_as_int(invl)));
    int n = q0 + crow;
    unsigned short* dst = &ao[(bb * 1024 + n) * 768 + head * 64];
    dst[l31] = f2bf(O0[r] * il);
    dst[32 + l31] = f2bf(O1[r] * il);
  }
}

extern "C" void kernel_launch(void* const* d_in, const int* in_sizes, int n_in,
                              void* d_out, int out_size, void* d_ws, size_t ws_size,
                              hipStream_t stream) {
  const float* x      = (const float*)d_in[0];
  const float* qkv_w  = (const float*)d_in[1];
  const float* qkv_b  = (const float*)d_in[2];
  const float* proj_w = (const float*)d_in[3];
  const float* proj_b = (const float*)d_in[4];
  const float* rph    = (const float*)d_in[5];
  const float* rpw    = (const float*)d_in[6];
  float* out = (float*)d_out;

  char* ws = (char*)d_ws;
  unsigned short* xb    = (unsigned short*)(ws);              // 6.29MB, dead after gemm<0>
  float*          relh  = (float*)(ws);                       // reuses xb region (exactly 6.29MB)
  unsigned short* wqkv  = (unsigned short*)(ws + 6291456);
  unsigned short* wproj = (unsigned short*)(ws + 9830400);
  unsigned short* qb    = (unsigned short*)(ws + 11010048);
  unsigned short* kb    = (unsigned short*)(ws + 17301504);
  unsigned short* vb    = (unsigned short*)(ws + 23592960);   // dead after vtrans
  unsigned short* ao    = (unsigned short*)(ws + 23592960);   // reuses vb region
  unsigned short* vt    = (unsigned short*)(ws + 29884416);
  unsigned short* relwb = (unsigned short*)(ws + 36175872);   // 3.15MB, end 39.3MB

  cvt_f32_bf16<<<3072, 256, 0, stream>>>(x, xb, 786432);
  cvt_f32_bf16<<<1728, 256, 0, stream>>>(qkv_w, wqkv, 442368);
  cvt_f32_bf16<<<576, 256, 0, stream>>>(proj_w, wproj, 147456);

  gemm_bf16<0><<<dim3(18, 32), 256, 0, stream>>>(xb, wqkv, qkv_b, nullptr, qb, kb, vb);
  vtrans<<<dim3(16, 48), 256, 0, stream>>>(vb, vt);
  rel_mfma16<<<dim3(32, 48), 64, 0, stream>>>(qb, rph, rpw, relwb, relh);
  attn2<<<1536, 64, 0, stream>>>(kb, vt, qb, relwb, relh, ao);
  gemm_bf16<1><<<dim3(6, 32), 256, 0, stream>>>(ao, wproj, proj_b, out, nullptr, nullptr, nullptr);
}

// Round 11
// 114.661 us; speedup vs baseline: 1.1490x; 1.1490x over previous
//
#include <hip/hip_runtime.h>

#define DEV_INLINE static __device__ __forceinline__

typedef __attribute__((ext_vector_type(8))) short bf16x8;
typedef __attribute__((ext_vector_type(4))) float f32x4;
typedef __attribute__((ext_vector_type(16))) float f32x16;

DEV_INLINE unsigned short f2bf(float f) {
  union { float f; unsigned int u; } v; v.f = f;
  unsigned int u = v.u;
  u += 0x7FFFu + ((u >> 16) & 1u);   // RNE
  return (unsigned short)(u >> 16);
}
DEV_INLINE float bf2f(unsigned short h) {
  union { unsigned int u; float f; } v; v.u = ((unsigned int)h) << 16; return v.f;
}

// ---------------- fp32 -> bf16 conversion ----------------
__global__ __launch_bounds__(256) void cvt_f32_bf16(const float* __restrict__ in,
                                                    unsigned short* __restrict__ out, int n4) {
  int i = blockIdx.x * 256 + threadIdx.x;
  if (i >= n4) return;
  float4 v = reinterpret_cast<const float4*>(in)[i];
  ushort4 o;
  o.x = f2bf(v.x); o.y = f2bf(v.y); o.z = f2bf(v.z); o.w = f2bf(v.w);
  reinterpret_cast<ushort4*>(out)[i] = o;
}

// ---------------- GEMM: C[M,N] = A[M,768] * B[N,768]^T (+bias) ----------------
// 3-buffer deep pipeline (r9-proven): counted vmcnt + raw s_barrier, BK=32,
// global_load_lds width=16, XOR involution.
// MODE 0: qkv scatter; q scaled by log2e, k scaled by 0.125
// MODE 1: output projection, fp32 out [4096][768]
template <int MODE>
__global__ __launch_bounds__(256) void gemm_bf16(const unsigned short* __restrict__ A,
                                                 const unsigned short* __restrict__ Bw,
                                                 const float* __restrict__ bias,
                                                 float* __restrict__ outF,
                                                 unsigned short* __restrict__ qo,
                                                 unsigned short* __restrict__ ko,
                                                 unsigned short* __restrict__ vo) {
  __shared__ unsigned short As[3][128 * 32];
  __shared__ unsigned short Bs[3][128 * 32];

  const int tid = threadIdx.x;
  const int lane = tid & 63;
  const int wv = tid >> 6;
  const int wrow = (wv >> 1) * 64;
  const int wcol = (wv & 1) * 64;
  const int m0 = blockIdx.y * 128;
  const int n0 = blockIdx.x * 128;
  const int l15 = lane & 15;
  const int lg = lane >> 4;

  const int srow = lane >> 2;                  // 0..15 within a 16-row chunk
  const int seg  = (lane & 3) ^ (srow & 3);    // pre-swizzled global k-segment

  f32x4 acc[4][4];
#pragma unroll
  for (int i = 0; i < 4; ++i)
#pragma unroll
    for (int j = 0; j < 4; ++j) acc[i][j] = (f32x4){0.f, 0.f, 0.f, 0.f};

#define GSTAGE(KT, B)                                                                        \
  do {                                                                                       \
    _Pragma("unroll") for (int pp = 0; pp < 2; ++pp) {                                       \
      int p = wv * 2 + pp;                     /* 16-row chunk, wave-uniform */              \
      int row = p * 16 + srow;                                                               \
      const unsigned short* ga = &A[(m0 + row) * 768 + (KT) * 32 + seg * 8];                 \
      __builtin_amdgcn_global_load_lds(                                                      \
          (const __attribute__((address_space(1))) unsigned int*)ga,                         \
          (__attribute__((address_space(3))) unsigned int*)&As[B][p * 512], 16, 0, 0);       \
      const unsigned short* gb = &Bw[(n0 + row) * 768 + (KT) * 32 + seg * 8];                \
      __builtin_amdgcn_global_load_lds(                                                      \
          (const __attribute__((address_space(1))) unsigned int*)gb,                         \
          (__attribute__((address_space(3))) unsigned int*)&Bs[B][p * 512], 16, 0, 0);       \
    }                                                                                        \
  } while (0)

  GSTAGE(0, 0);
  GSTAGE(1, 1);

  const int soff = (lg ^ (l15 & 3)) * 8;       // read-side of the involution

#pragma unroll
  for (int kt = 0; kt < 24; ++kt) {
    const int b = kt % 3;
    // wait for tile kt only; tile kt+1's 4 loads stay in flight across the barrier
    if (kt < 23) asm volatile("s_waitcnt vmcnt(4)" ::: "memory");
    else         asm volatile("s_waitcnt vmcnt(0)" ::: "memory");
    __builtin_amdgcn_s_barrier();
    asm volatile("" ::: "memory");
    if (kt < 22) GSTAGE(kt + 2, (kt + 2) % 3);  // into buffer freed at kt-1

    bf16x8 aF[4], bF[4];
#pragma unroll
    for (int i = 0; i < 4; ++i)
      aF[i] = *reinterpret_cast<const bf16x8*>(&As[b][(wrow + i * 16 + l15) * 32 + soff]);
#pragma unroll
    for (int j = 0; j < 4; ++j)
      bF[j] = *reinterpret_cast<const bf16x8*>(&Bs[b][(wcol + j * 16 + l15) * 32 + soff]);
#pragma unroll
    for (int i = 0; i < 4; ++i)
#pragma unroll
      for (int j = 0; j < 4; ++j)
        acc[i][j] = __builtin_amdgcn_mfma_f32_16x16x32_bf16(aF[i], bF[j], acc[i][j], 0, 0, 0);
  }
#undef GSTAGE

#pragma unroll
  for (int i = 0; i < 4; ++i) {
#pragma unroll
    for (int j = 0; j < 4; ++j) {
#pragma unroll
      for (int r = 0; r < 4; ++r) {
        int row = m0 + wrow + i * 16 + (lane >> 4) * 4 + r;
        int col = n0 + wcol + j * 16 + l15;
        float val = acc[i][j][r] + bias[col];
        if (MODE == 0) {
          int t = col / 768;
          int rem = col - t * 768;
          int head = rem >> 6;
          int c = rem & 63;
          int bb = row >> 10;
          int n = row & 1023;
          if (t == 0) val *= 1.44269504f; // fold log2e into Q (exp2-domain softmax)
          if (t == 1) val *= 0.125f;      // fold q-scale into K
          unsigned short* dst = (t == 0) ? qo : (t == 1) ? ko : vo;
          dst[((bb * 12 + head) * 1024 + n) * 64 + c] = f2bf(val);
        } else {
          outF[row * 768 + col] = val;
        }
      }
    }
  }
}

// ---------------- V transpose: [48][1024][64] -> [48][64][1024] ----------------
__global__ __launch_bounds__(256) void vtrans(const unsigned short* __restrict__ vb,
                                              unsigned short* __restrict__ vt) {
  __shared__ unsigned short t[64][72];
  const int n0 = blockIdx.x * 64;
  const int bh = blockIdx.y;
  const int tid = threadIdx.x;
#pragma unroll
  for (int i = 0; i < 4; ++i) {
    int s = tid + i * 256;
    int row = s >> 4, c4 = (s & 15) * 4;
    *reinterpret_cast<ushort4*>(&t[row][c4]) =
        *reinterpret_cast<const ushort4*>(&vb[(bh * 1024 + n0 + row) * 64 + c4]);
  }
  __syncthreads();
#pragma unroll
  for (int i = 0; i < 4; ++i) {
    int s = tid + i * 256;
    int d = s >> 4, n4 = (s & 15) * 4;
    ushort4 o;
    o.x = t[n4 + 0][d]; o.y = t[n4 + 1][d]; o.z = t[n4 + 2][d]; o.w = t[n4 + 3][d];
    *reinterpret_cast<ushort4*>(&vt[(bh * 64 + d) * 1024 + n0 + n4]) = o;
  }
}

// ---------------- rel-pos via 16x16x32 MFMA (gemm-verified conventions) ----------------
// Input q is already scaled by log2e -> relh/relwb come out in log2 units.
DEV_INLINE f32x4 mfma16(bf16x8 a, bf16x8 b, f32x4 c) {
  return __builtin_amdgcn_mfma_f32_16x16x32_bf16(a, b, c, 0, 0, 0);
}

__global__ __launch_bounds__(64) void rel_mfma16(const unsigned short* __restrict__ q,
                                                 const float* __restrict__ rph,
                                                 const float* __restrict__ rpw,
                                                 unsigned short* __restrict__ relwb,
                                                 float* __restrict__ relh) {
  __shared__ unsigned short qs[32 * 72];
  __shared__ unsigned short rhh[32 * 72], rhl[32 * 72];
  __shared__ unsigned short rwh[64 * 72], rwl[64 * 72];
  __shared__ float relh_s[32 * 36];
  __shared__ unsigned short relw_s[32 * 40];

  const int lane = threadIdx.x;
  const int l15 = lane & 15;
  const int lg = lane >> 4;
  const int qh = blockIdx.x;   // 0..31
  const int bh = blockIdx.y;   // 0..47

#pragma unroll
  for (int it = 0; it < 4; ++it) {
    int s = lane + it * 64;
    int row = s >> 3, ch = s & 7;
    *reinterpret_cast<int4*>(&qs[row * 72 + ch * 8]) =
        *reinterpret_cast<const int4*>(&q[(bh * 1024 + qh * 32 + row) * 64 + ch * 8]);
  }
#pragma unroll
  for (int it = 0; it < 8; ++it) {
    int s = lane + it * 64;
    int row = s >> 4, c4 = (s & 15) * 4;
    float4 v = *reinterpret_cast<const float4*>(&rph[(qh + row) * 64 + c4]);
    ushort4 h, l;
    h.x = f2bf(v.x); l.x = f2bf(v.x - bf2f(h.x));
    h.y = f2bf(v.y); l.y = f2bf(v.y - bf2f(h.y));
    h.z = f2bf(v.z); l.z = f2bf(v.z - bf2f(h.z));
    h.w = f2bf(v.w); l.w = f2bf(v.w - bf2f(h.w));
    *reinterpret_cast<ushort4*>(&rhh[row * 72 + c4]) = h;
    *reinterpret_cast<ushort4*>(&rhl[row * 72 + c4]) = l;
  }
#pragma unroll
  for (int it = 0; it < 16; ++it) {
    int s = lane + it * 64;
    int row = s >> 4, c4 = (s & 15) * 4;
    float4 v = (float4){0.f, 0.f, 0.f, 0.f};
    if (row < 63) v = *reinterpret_cast<const float4*>(&rpw[row * 64 + c4]);
    ushort4 h, l;
    h.x = f2bf(v.x); l.x = f2bf(v.x - bf2f(h.x));
    h.y = f2bf(v.y); l.y = f2bf(v.y - bf2f(h.y));
    h.z = f2bf(v.z); l.z = f2bf(v.z - bf2f(h.z));
    h.w = f2bf(v.w); l.w = f2bf(v.w - bf2f(h.w));
    *reinterpret_cast<ushort4*>(&rwh[row * 72 + c4]) = h;
    *reinterpret_cast<ushort4*>(&rwl[row * 72 + c4]) = l;
  }
  __syncthreads();

  const int k0 = lg * 8, k1 = 32 + lg * 8;
  bf16x8 fq[2][2], fhh[2][2], fhl[2][2], fwh[4][2], fwl[4][2];
#pragma unroll
  for (int t = 0; t < 2; ++t) {
    fq[t][0]  = *reinterpret_cast<const bf16x8*>(&qs[(t * 16 + l15) * 72 + k0]);
    fq[t][1]  = *reinterpret_cast<const bf16x8*>(&qs[(t * 16 + l15) * 72 + k1]);
    fhh[t][0] = *reinterpret_cast<const bf16x8*>(&rhh[(t * 16 + l15) * 72 + k0]);
    fhh[t][1] = *reinterpret_cast<const bf16x8*>(&rhh[(t * 16 + l15) * 72 + k1]);
    fhl[t][0] = *reinterpret_cast<const bf16x8*>(&rhl[(t * 16 + l15) * 72 + k0]);
    fhl[t][1] = *reinterpret_cast<const bf16x8*>(&rhl[(t * 16 + l15) * 72 + k1]);
  }
#pragma unroll
  for (int t = 0; t < 4; ++t) {
    fwh[t][0] = *reinterpret_cast<const bf16x8*>(&rwh[(t * 16 + l15) * 72 + k0]);
    fwh[t][1] = *reinterpret_cast<const bf16x8*>(&rwh[(t * 16 + l15) * 72 + k1]);
    fwl[t][0] = *reinterpret_cast<const bf16x8*>(&rwl[(t * 16 + l15) * 72 + k0]);
    fwl[t][1] = *reinterpret_cast<const bf16x8*>(&rwl[(t * 16 + l15) * 72 + k1]);
  }

  f32x4 ah[2][2];
#pragma unroll
  for (int i = 0; i < 2; ++i)
#pragma unroll
    for (int jj = 0; jj < 2; ++jj) {
      f32x4 a = (f32x4){0.f, 0.f, 0.f, 0.f};
      a = mfma16(fhh[i][0], fq[jj][0], a);
      a = mfma16(fhh[i][1], fq[jj][1], a);
      a = mfma16(fhl[i][0], fq[jj][0], a);
      a = mfma16(fhl[i][1], fq[jj][1], a);
      ah[i][jj] = a;
    }
  f32x4 aw[2][4];
#pragma unroll
  for (int i = 0; i < 2; ++i)
#pragma unroll
    for (int jj = 0; jj < 4; ++jj) {
      f32x4 a = (f32x4){0.f, 0.f, 0.f, 0.f};
      a = mfma16(fq[i][0], fwh[jj][0], a);
      a = mfma16(fq[i][1], fwh[jj][1], a);
      a = mfma16(fq[i][0], fwl[jj][0], a);
      a = mfma16(fq[i][1], fwl[jj][1], a);
      aw[i][jj] = a;
    }

#pragma unroll
  for (int i = 0; i < 2; ++i)
#pragma unroll
    for (int jj = 0; jj < 2; ++jj)
#pragma unroll
      for (int r = 0; r < 4; ++r) {
        int t = i * 16 + lg * 4 + r;
        int qw = jj * 16 + l15;
        relh_s[qw * 36 + 31 - t] = ah[i][jj][r];
      }
#pragma unroll
  for (int i = 0; i < 2; ++i)
#pragma unroll
    for (int jj = 0; jj < 4; ++jj)
#pragma unroll
      for (int r = 0; r < 4; ++r) {
        int qw = i * 16 + lg * 4 + r;
        int d = jj * 16 + l15;
        int kw = qw + 31 - d;
        if (kw >= 0 && kw < 32) relw_s[qw * 40 + kw] = f2bf(aw[i][jj][r]);
      }
  __syncthreads();

#pragma unroll
  for (int it = 0; it < 4; ++it) {
    int s = lane + it * 64;
    int row = s >> 3, c4 = (s & 7) * 4;
    *reinterpret_cast<float4*>(&relh[(bh * 1024 + qh * 32 + row) * 32 + c4]) =
        *reinterpret_cast<const float4*>(&relh_s[row * 36 + c4]);
  }
#pragma unroll
  for (int it = 0; it < 2; ++it) {
    int s = lane + it * 64;
    int row = s >> 2, ch = s & 3;
    *reinterpret_cast<int4*>(&relwb[(bh * 1024 + qh * 32 + row) * 32 + ch * 8]) =
        *reinterpret_cast<const int4*>(&relw_s[row * 40 + ch * 8]);
  }
}

// ---------------- flash attention (r8-proven): swapped-QK^T 32x32, 2-buffer LDS,
// __syncthreads-drained prefetch, exp2 domain, setprio, bhv prefetch ----------------
DEV_INLINE f32x16 mfma32(bf16x8 a, bf16x8 b, f32x16 c) {
  return __builtin_amdgcn_mfma_f32_32x32x16_bf16(a, b, c, 0, 0, 0);
}

DEV_INLINE bf16x8 make_pa(const float* p) {
  unsigned int W0, W1, W2, W3;
  asm("v_cvt_pk_bf16_f32 %0, %1, %2" : "=v"(W0) : "v"(p[0]), "v"(p[1]));
  asm("v_cvt_pk_bf16_f32 %0, %1, %2" : "=v"(W1) : "v"(p[2]), "v"(p[3]));
  asm("v_cvt_pk_bf16_f32 %0, %1, %2" : "=v"(W2) : "v"(p[4]), "v"(p[5]));
  asm("v_cvt_pk_bf16_f32 %0, %1, %2" : "=v"(W3) : "v"(p[6]), "v"(p[7]));
  asm("v_permlane32_swap_b32 %0, %1" : "+v"(W0), "+v"(W2));
  asm("v_permlane32_swap_b32 %0, %1" : "+v"(W1), "+v"(W3));
  union { unsigned int w[4]; bf16x8 v; } u;
  u.w[0] = W0; u.w[1] = W1; u.w[2] = W2; u.w[3] = W3;
  return u.v;
}

__global__ __launch_bounds__(128) void attn2(const unsigned short* __restrict__ kg,
                                             const unsigned short* __restrict__ vtg,
                                             const unsigned short* __restrict__ qg,
                                             const unsigned short* __restrict__ relwb,
                                             const float* __restrict__ relh,
                                             unsigned short* __restrict__ ao) {
  __shared__ unsigned short k_lin[2][64 * 64];
  __shared__ unsigned short v_lin[2][64 * 64];

  const int tid = threadIdx.x;
  const int lane = tid & 63;
  const int wv = tid >> 6;
  const int l31 = lane & 31;
  const int hi = lane >> 5;

  const int bid = blockIdx.x;
  const int swz = (bid & 7) * 96 + (bid >> 3);   // XCD-chunked: 6 bh per XCD
  const int bh = swz >> 4;
  const int qt = swz & 15;
  const int q0 = qt * 64 + wv * 32;

  bf16x8 qf[6];
  {
    const unsigned short* qrow = &qg[(bh * 1024 + q0 + l31) * 64 + hi * 8];
#pragma unroll
    for (int c = 0; c < 4; ++c)
      qf[c] = *reinterpret_cast<const bf16x8*>(&qrow[c * 16]);
    const unsigned short* wrow = &relwb[(bh * 1024 + q0 + l31) * 32 + hi * 8];
    qf[4] = *reinterpret_cast<const bf16x8*>(&wrow[0]);
    qf[5] = *reinterpret_cast<const bf16x8*>(&wrow[16]);
  }

  bf16x8 ohf0, ohf1;
  {
    int t0 = l31 - 8 * hi;
    int t1 = l31 - 16 - 8 * hi;
    union { unsigned int w[4]; bf16x8 v; } u0, u1;
#pragma unroll
    for (int w = 0; w < 4; ++w) {
      u0.w[w] = (t0 >= 0 && (t0 >> 1) == w) ? ((t0 & 1) ? 0x3F800000u : 0x3F80u) : 0u;
      u1.w[w] = (t1 >= 0 && (t1 >> 1) == w) ? ((t1 & 1) ? 0x3F800000u : 0x3F80u) : 0u;
    }
    ohf0 = u0.v; ohf1 = u1.v;
  }

  f32x16 O0, O1;
#pragma unroll
  for (int r = 0; r < 16; ++r) { O0[r] = 0.f; O1[r] = 0.f; }
  float m_r = -3.0e38f, l_r = 0.f;

  const int srow = lane >> 3;
  const int scb = (lane & 7) ^ srow;
  const int rsw = l31 & 7;

#define STAGE(KT, B)                                                                       \
  do {                                                                                     \
    _Pragma("unroll") for (int pp = 0; pp < 4; ++pp) {                                     \
      int p = wv * 4 + pp;                                                                 \
      int row = p * 8 + srow;                                                              \
      const unsigned short* gk = &kg[(bh * 1024 + (KT) * 64 + row) * 64 + scb * 8];        \
      __builtin_amdgcn_global_load_lds(                                                    \
          (const __attribute__((address_space(1))) unsigned int*)gk,                       \
          (__attribute__((address_space(3))) unsigned int*)&k_lin[B][p * 512], 16, 0, 0);  \
      const unsigned short* gv = &vtg[(bh * 64 + row) * 1024 + (KT) * 64 + scb * 8];       \
      __builtin_amdgcn_global_load_lds(                                                    \
          (const __attribute__((address_space(1))) unsigned int*)gv,                       \
          (__attribute__((address_space(3))) unsigned int*)&v_lin[B][p * 512], 16, 0, 0);  \
    }                                                                                      \
  } while (0)

  STAGE(0, 0);

  const float* rhrow = &relh[(bh * 1024 + q0 + l31) * 32];
  float2 bhv = *reinterpret_cast<const float2*>(&rhrow[0]);

  for (int kt = 0; kt < 16; ++kt) {
    const int b = kt & 1;
    __syncthreads();                       // drains vmcnt -> buf b valid
    if (kt < 15) STAGE(kt + 1, b ^ 1);     // prefetch in flight during compute

    float2 bhv_next = bhv;
    if (kt < 15) bhv_next = *reinterpret_cast<const float2*>(&rhrow[2 * (kt + 1)]);
    float bh0 = bhv.x, bh1 = bhv.y;

    f32x16 s0, s1;
#pragma unroll
    for (int r = 0; r < 16; ++r) { s0[r] = 0.f; s1[r] = 0.f; }
    {
      const unsigned short* kb0 = &k_lin[b][l31 * 64];
      const unsigned short* kb1 = &k_lin[b][(32 + l31) * 64];
      __builtin_amdgcn_s_setprio(1);
#pragma unroll
      for (int c = 0; c < 4; ++c) {
        int cb = ((2 * c + hi) ^ rsw) * 8;
        s0 = mfma32(*reinterpret_cast<const bf16x8*>(&kb0[cb]), qf[c], s0);
        s1 = mfma32(*reinterpret_cast<const bf16x8*>(&kb1[cb]), qf[c], s1);
      }
      s0 = mfma32(ohf0, qf[4], s0);
      s0 = mfma32(ohf1, qf[5], s0);
      s1 = mfma32(ohf0, qf[4], s1);
      s1 = mfma32(ohf1, qf[5], s1);
      __builtin_amdgcn_s_setprio(0);
    }

    float pm0 = s0[0], pm1 = s1[0];
#pragma unroll
    for (int r = 1; r < 16; ++r) { pm0 = fmaxf(pm0, s0[r]); pm1 = fmaxf(pm1, s1[r]); }
    float pmax = fmaxf(pm0 + bh0, pm1 + bh1);
    pmax = fmaxf(pmax, __shfl_xor(pmax, 32));

    if (!__all(pmax <= m_r + 11.5f)) {     // defer-max (log2 units): rescale is rare
      float mnew = fmaxf(m_r, pmax);
      float corr = __builtin_amdgcn_exp2f(m_r - mnew);
      m_r = mnew;
      l_r *= corr;
#pragma unroll
      for (int r = 0; r < 16; ++r) {
        int cr = ((r & 3) + 8 * (r >> 2) + 4 * hi) << 2;
        float c2 = __int_as_float(__builtin_amdgcn_ds_bpermute(cr, __float_as_int(corr)));
        O0[r] *= c2;
        O1[r] *= c2;
      }
    }

    float mb0 = m_r - bh0, mb1 = m_r - bh1;
    float p0[16], p1[16];
    float ps = 0.f;
#pragma unroll
    for (int r = 0; r < 16; ++r) { p0[r] = __builtin_amdgcn_exp2f(s0[r] - mb0); ps += p0[r]; }
#pragma unroll
    for (int r = 0; r < 16; ++r) { p1[r] = __builtin_amdgcn_exp2f(s1[r] - mb1); ps += p1[r]; }
    ps += __shfl_xor(ps, 32);
    l_r += ps;

    bf16x8 pa0 = make_pa(p0 + 0);
    bf16x8 pa1 = make_pa(p0 + 8);
    bf16x8 pa2 = make_pa(p1 + 0);
    bf16x8 pa3 = make_pa(p1 + 8);

    const unsigned short* vb0 = &v_lin[b][l31 * 64];
    const unsigned short* vb1 = &v_lin[b][(32 + l31) * 64];
    __builtin_amdgcn_s_setprio(1);
#pragma unroll
    for (int c = 0; c < 4; ++c) {
      bf16x8 pac = (c == 0) ? pa0 : (c == 1) ? pa1 : (c == 2) ? pa2 : pa3;
      int cb = ((2 * c + hi) ^ rsw) * 8;
      O0 = mfma32(pac, *reinterpret_cast<const bf16x8*>(&vb0[cb]), O0);
      O1 = mfma32(pac, *reinterpret_cast<const bf16x8*>(&vb1[cb]), O1);
    }
    __builtin_amdgcn_s_setprio(0);

    bhv = bhv_next;
  }
#undef STAGE

  float invl = 1.f / l_r;
  const int bb = bh / 12, head = bh % 12;
#pragma unroll
  for (int r = 0; r < 16; ++r) {
    int crow = (r & 3) + 8 * (r >> 2) + 4 * hi;
    float il = __int_as_float(__builtin_amdgcn_ds_bpermute(crow << 2, __float_as_int(invl)));
    int n = q0 + crow;
    unsigned short* dst = &ao[(bb * 1024 + n) * 768 + head * 64];
    dst[l31] = f2bf(O0[r] * il);
    dst[32 + l31] = f2bf(O1[r] * il);
  }
}

extern "C" void kernel_launch(void* const* d_in, const int* in_sizes, int n_in,
                              void* d_out, int out_size, void* d_ws, size_t ws_size,
                              hipStream_t stream) {
  const float* x      = (const float*)d_in[0];
  const float* qkv_w  = (const float*)d_in[1];
  const float* qkv_b  = (const float*)d_in[2];
  const float* proj_w = (const float*)d_in[3];
  const float* proj_b = (const float*)d_in[4];
  const float* rph    = (const float*)d_in[5];
  const float* rpw    = (const float*)d_in[6];
  float* out = (float*)d_out;

  char* ws = (char*)d_ws;
  unsigned short* xb    = (unsigned short*)(ws);              // 6.29MB, dead after gemm<0>
  float*          relh  = (float*)(ws);                       // reuses xb region (exactly 6.29MB)
  unsigned short* wqkv  = (unsigned short*)(ws + 6291456);
  unsigned short* wproj = (unsigned short*)(ws + 9830400);
  unsigned short* qb    = (unsigned short*)(ws + 11010048);
  unsigned short* kb    = (unsigned short*)(ws + 17301504);
  unsigned short* vb    = (unsigned short*)(ws + 23592960);   // dead after vtrans
  unsigned short* ao    = (unsigned short*)(ws + 23592960);   // reuses vb region
  unsigned short* vt    = (unsigned short*)(ws + 29884416);
  unsigned short* relwb = (unsigned short*)(ws + 36175872);   // 3.15MB, end 39.3MB

  cvt_f32_bf16<<<3072, 256, 0, stream>>>(x, xb, 786432);
  cvt_f32_bf16<<<1728, 256, 0, stream>>>(qkv_w, wqkv, 442368);
  cvt_f32_bf16<<<576, 256, 0, stream>>>(proj_w, wproj, 147456);

  gemm_bf16<0><<<dim3(18, 32), 256, 0, stream>>>(xb, wqkv, qkv_b, nullptr, qb, kb, vb);
  vtrans<<<dim3(16, 48), 256, 0, stream>>>(vb, vt);
  rel_mfma16<<<dim3(32, 48), 64, 0, stream>>>(qb, rph, rpw, relwb, relh);
  attn2<<<768, 128, 0, stream>>>(kb, vt, qb, relwb, relh, ao);
  gemm_bf16<1><<<dim3(6, 32), 256, 0, stream>>>(ao, wproj, proj_b, out, nullptr, nullptr, nullptr);
}

// Round 12
// 110.041 us; speedup vs baseline: 1.1972x; 1.0420x over previous
//
#include <hip/hip_runtime.h>

#define DEV_INLINE static __device__ __forceinline__

typedef __attribute__((ext_vector_type(8))) short bf16x8;
typedef __attribute__((ext_vector_type(4))) float f32x4;
typedef __attribute__((ext_vector_type(16))) float f32x16;

DEV_INLINE unsigned short f2bf(float f) {
  union { float f; unsigned int u; } v; v.f = f;
  unsigned int u = v.u;
  u += 0x7FFFu + ((u >> 16) & 1u);   // RNE
  return (unsigned short)(u >> 16);
}
DEV_INLINE float bf2f(unsigned short h) {
  union { unsigned int u; float f; } v; v.u = ((unsigned int)h) << 16; return v.f;
}

// ---------------- fused fp32 -> bf16 conversion (x, qkv_w, proj_w in one launch) ----------------
__global__ __launch_bounds__(256) void cvt_all(const float* __restrict__ x,
                                               const float* __restrict__ qw,
                                               const float* __restrict__ pw,
                                               unsigned short* __restrict__ xb,
                                               unsigned short* __restrict__ wqkv,
                                               unsigned short* __restrict__ wproj) {
  const int bid = blockIdx.x;
  const float* in;
  unsigned short* out;
  int i;
  if (bid < 3072)      { in = x;  out = xb;    i = bid * 256 + threadIdx.x; }
  else if (bid < 4800) { in = qw; out = wqkv;  i = (bid - 3072) * 256 + threadIdx.x; }
  else                 { in = pw; out = wproj; i = (bid - 4800) * 256 + threadIdx.x; }
  float4 v = reinterpret_cast<const float4*>(in)[i];
  ushort4 o;
  o.x = f2bf(v.x); o.y = f2bf(v.y); o.z = f2bf(v.z); o.w = f2bf(v.w);
  reinterpret_cast<ushort4*>(out)[i] = o;
}

// ---------------- GEMM: C[M,N] = A[M,768] * B[N,768]^T (+bias) ----------------
// 3-buffer deep pipeline (r9-proven): counted vmcnt + raw s_barrier, BK=32,
// global_load_lds width=16, XOR involution.
// MODE 0: qkv scatter; q scaled by log2e, k scaled by 0.125
// MODE 1: output projection, fp32 out [4096][768]
template <int MODE>
__global__ __launch_bounds__(256) void gemm_bf16(const unsigned short* __restrict__ A,
                                                 const unsigned short* __restrict__ Bw,
                                                 const float* __restrict__ bias,
                                                 float* __restrict__ outF,
                                                 unsigned short* __restrict__ qo,
                                                 unsigned short* __restrict__ ko,
                                                 unsigned short* __restrict__ vo) {
  __shared__ unsigned short As[3][128 * 32];
  __shared__ unsigned short Bs[3][128 * 32];

  const int tid = threadIdx.x;
  const int lane = tid & 63;
  const int wv = tid >> 6;
  const int wrow = (wv >> 1) * 64;
  const int wcol = (wv & 1) * 64;
  const int m0 = blockIdx.y * 128;
  const int n0 = blockIdx.x * 128;
  const int l15 = lane & 15;
  const int lg = lane >> 4;

  const int srow = lane >> 2;                  // 0..15 within a 16-row chunk
  const int seg  = (lane & 3) ^ (srow & 3);    // pre-swizzled global k-segment

  f32x4 acc[4][4];
#pragma unroll
  for (int i = 0; i < 4; ++i)
#pragma unroll
    for (int j = 0; j < 4; ++j) acc[i][j] = (f32x4){0.f, 0.f, 0.f, 0.f};

#define GSTAGE(KT, B)                                                                        \
  do {                                                                                       \
    _Pragma("unroll") for (int pp = 0; pp < 2; ++pp) {                                       \
      int p = wv * 2 + pp;                     /* 16-row chunk, wave-uniform */              \
      int row = p * 16 + srow;                                                               \
      const unsigned short* ga = &A[(m0 + row) * 768 + (KT) * 32 + seg * 8];                 \
      __builtin_amdgcn_global_load_lds(                                                      \
          (const __attribute__((address_space(1))) unsigned int*)ga,                         \
          (__attribute__((address_space(3))) unsigned int*)&As[B][p * 512], 16, 0, 0);       \
      const unsigned short* gb = &Bw[(n0 + row) * 768 + (KT) * 32 + seg * 8];                \
      __builtin_amdgcn_global_load_lds(                                                      \
          (const __attribute__((address_space(1))) unsigned int*)gb,                         \
          (__attribute__((address_space(3))) unsigned int*)&Bs[B][p * 512], 16, 0, 0);       \
    }                                                                                        \
  } while (0)

  GSTAGE(0, 0);
  GSTAGE(1, 1);

  const int soff = (lg ^ (l15 & 3)) * 8;       // read-side of the involution

#pragma unroll
  for (int kt = 0; kt < 24; ++kt) {
    const int b = kt % 3;
    // wait for tile kt only; tile kt+1's 4 loads stay in flight across the barrier
    if (kt < 23) asm volatile("s_waitcnt vmcnt(4)" ::: "memory");
    else         asm volatile("s_waitcnt vmcnt(0)" ::: "memory");
    __builtin_amdgcn_s_barrier();
    asm volatile("" ::: "memory");
    if (kt < 22) GSTAGE(kt + 2, (kt + 2) % 3);  // into buffer freed at kt-1

    bf16x8 aF[4], bF[4];
#pragma unroll
    for (int i = 0; i < 4; ++i)
      aF[i] = *reinterpret_cast<const bf16x8*>(&As[b][(wrow + i * 16 + l15) * 32 + soff]);
#pragma unroll
    for (int j = 0; j < 4; ++j)
      bF[j] = *reinterpret_cast<const bf16x8*>(&Bs[b][(wcol + j * 16 + l15) * 32 + soff]);
#pragma unroll
    for (int i = 0; i < 4; ++i)
#pragma unroll
      for (int j = 0; j < 4; ++j)
        acc[i][j] = __builtin_amdgcn_mfma_f32_16x16x32_bf16(aF[i], bF[j], acc[i][j], 0, 0, 0);
  }
#undef GSTAGE

#pragma unroll
  for (int i = 0; i < 4; ++i) {
#pragma unroll
    for (int j = 0; j < 4; ++j) {
#pragma unroll
      for (int r = 0; r < 4; ++r) {
        int row = m0 + wrow + i * 16 + (lane >> 4) * 4 + r;
        int col = n0 + wcol + j * 16 + l15;
        float val = acc[i][j][r] + bias[col];
        if (MODE == 0) {
          int t = col / 768;
          int rem = col - t * 768;
          int head = rem >> 6;
          int c = rem & 63;
          int bb = row >> 10;
          int n = row & 1023;
          if (t == 0) val *= 1.44269504f; // fold log2e into Q (exp2-domain softmax)
          if (t == 1) val *= 0.125f;      // fold q-scale into K
          unsigned short* dst = (t == 0) ? qo : (t == 1) ? ko : vo;
          dst[((bb * 12 + head) * 1024 + n) * 64 + c] = f2bf(val);
        } else {
          outF[row * 768 + col] = val;
        }
      }
    }
  }
}

// ---------------- V transpose: [48][1024][64] -> [48][64][1024] ----------------
__global__ __launch_bounds__(256) void vtrans(const unsigned short* __restrict__ vb,
                                              unsigned short* __restrict__ vt) {
  __shared__ unsigned short t[64][72];
  const int n0 = blockIdx.x * 64;
  const int bh = blockIdx.y;
  const int tid = threadIdx.x;
#pragma unroll
  for (int i = 0; i < 4; ++i) {
    int s = tid + i * 256;
    int row = s >> 4, c4 = (s & 15) * 4;
    *reinterpret_cast<ushort4*>(&t[row][c4]) =
        *reinterpret_cast<const ushort4*>(&vb[(bh * 1024 + n0 + row) * 64 + c4]);
  }
  __syncthreads();
#pragma unroll
  for (int i = 0; i < 4; ++i) {
    int s = tid + i * 256;
    int d = s >> 4, n4 = (s & 15) * 4;
    ushort4 o;
    o.x = t[n4 + 0][d]; o.y = t[n4 + 1][d]; o.z = t[n4 + 2][d]; o.w = t[n4 + 3][d];
    *reinterpret_cast<ushort4*>(&vt[(bh * 64 + d) * 1024 + n0 + n4]) = o;
  }
}

// ---------------- rel-pos via 16x16x32 MFMA (gemm-verified conventions) ----------------
// Input q is already scaled by log2e -> relh/relwb come out in log2 units.
DEV_INLINE f32x4 mfma16(bf16x8 a, bf16x8 b, f32x4 c) {
  return __builtin_amdgcn_mfma_f32_16x16x32_bf16(a, b, c, 0, 0, 0);
}

__global__ __launch_bounds__(64) void rel_mfma16(const unsigned short* __restrict__ q,
                                                 const float* __restrict__ rph,
                                                 const float* __restrict__ rpw,
                                                 unsigned short* __restrict__ relwb,
                                                 float* __restrict__ relh) {
  __shared__ unsigned short qs[32 * 72];
  __shared__ unsigned short rhh[32 * 72], rhl[32 * 72];
  __shared__ unsigned short rwh[64 * 72], rwl[64 * 72];
  __shared__ float relh_s[32 * 36];
  __shared__ unsigned short relw_s[32 * 40];

  const int lane = threadIdx.x;
  const int l15 = lane & 15;
  const int lg = lane >> 4;
  const int qh = blockIdx.x;   // 0..31
  const int bh = blockIdx.y;   // 0..47

#pragma unroll
  for (int it = 0; it < 4; ++it) {
    int s = lane + it * 64;
    int row = s >> 3, ch = s & 7;
    *reinterpret_cast<int4*>(&qs[row * 72 + ch * 8]) =
        *reinterpret_cast<const int4*>(&q[(bh * 1024 + qh * 32 + row) * 64 + ch * 8]);
  }
#pragma unroll
  for (int it = 0; it < 8; ++it) {
    int s = lane + it * 64;
    int row = s >> 4, c4 = (s & 15) * 4;
    float4 v = *reinterpret_cast<const float4*>(&rph[(qh + row) * 64 + c4]);
    ushort4 h, l;
    h.x = f2bf(v.x); l.x = f2bf(v.x - bf2f(h.x));
    h.y = f2bf(v.y); l.y = f2bf(v.y - bf2f(h.y));
    h.z = f2bf(v.z); l.z = f2bf(v.z - bf2f(h.z));
    h.w = f2bf(v.w); l.w = f2bf(v.w - bf2f(h.w));
    *reinterpret_cast<ushort4*>(&rhh[row * 72 + c4]) = h;
    *reinterpret_cast<ushort4*>(&rhl[row * 72 + c4]) = l;
  }
#pragma unroll
  for (int it = 0; it < 16; ++it) {
    int s = lane + it * 64;
    int row = s >> 4, c4 = (s & 15) * 4;
    float4 v = (float4){0.f, 0.f, 0.f, 0.f};
    if (row < 63) v = *reinterpret_cast<const float4*>(&rpw[row * 64 + c4]);
    ushort4 h, l;
    h.x = f2bf(v.x); l.x = f2bf(v.x - bf2f(h.x));
    h.y = f2bf(v.y); l.y = f2bf(v.y - bf2f(h.y));
    h.z = f2bf(v.z); l.z = f2bf(v.z - bf2f(h.z));
    h.w = f2bf(v.w); l.w = f2bf(v.w - bf2f(h.w));
    *reinterpret_cast<ushort4*>(&rwh[row * 72 + c4]) = h;
    *reinterpret_cast<ushort4*>(&rwl[row * 72 + c4]) = l;
  }
  __syncthreads();

  const int k0 = lg * 8, k1 = 32 + lg * 8;
  bf16x8 fq[2][2], fhh[2][2], fhl[2][2], fwh[4][2], fwl[4][2];
#pragma unroll
  for (int t = 0; t < 2; ++t) {
    fq[t][0]  = *reinterpret_cast<const bf16x8*>(&qs[(t * 16 + l15) * 72 + k0]);
    fq[t][1]  = *reinterpret_cast<const bf16x8*>(&qs[(t * 16 + l15) * 72 + k1]);
    fhh[t][0] = *reinterpret_cast<const bf16x8*>(&rhh[(t * 16 + l15) * 72 + k0]);
    fhh[t][1] = *reinterpret_cast<const bf16x8*>(&rhh[(t * 16 + l15) * 72 + k1]);
    fhl[t][0] = *reinterpret_cast<const bf16x8*>(&rhl[(t * 16 + l15) * 72 + k0]);
    fhl[t][1] = *reinterpret_cast<const bf16x8*>(&rhl[(t * 16 + l15) * 72 + k1]);
  }
#pragma unroll
  for (int t = 0; t < 4; ++t) {
    fwh[t][0] = *reinterpret_cast<const bf16x8*>(&rwh[(t * 16 + l15) * 72 + k0]);
    fwh[t][1] = *reinterpret_cast<const bf16x8*>(&rwh[(t * 16 + l15) * 72 + k1]);
    fwl[t][0] = *reinterpret_cast<const bf16x8*>(&rwl[(t * 16 + l15) * 72 + k0]);
    fwl[t][1] = *reinterpret_cast<const bf16x8*>(&rwl[(t * 16 + l15) * 72 + k1]);
  }

  f32x4 ah[2][2];
#pragma unroll
  for (int i = 0; i < 2; ++i)
#pragma unroll
    for (int jj = 0; jj < 2; ++jj) {
      f32x4 a = (f32x4){0.f, 0.f, 0.f, 0.f};
      a = mfma16(fhh[i][0], fq[jj][0], a);
      a = mfma16(fhh[i][1], fq[jj][1], a);
      a = mfma16(fhl[i][0], fq[jj][0], a);
      a = mfma16(fhl[i][1], fq[jj][1], a);
      ah[i][jj] = a;
    }
  f32x4 aw[2][4];
#pragma unroll
  for (int i = 0; i < 2; ++i)
#pragma unroll
    for (int jj = 0; jj < 4; ++jj) {
      f32x4 a = (f32x4){0.f, 0.f, 0.f, 0.f};
      a = mfma16(fq[i][0], fwh[jj][0], a);
      a = mfma16(fq[i][1], fwh[jj][1], a);
      a = mfma16(fq[i][0], fwl[jj][0], a);
      a = mfma16(fq[i][1], fwl[jj][1], a);
      aw[i][jj] = a;
    }

#pragma unroll
  for (int i = 0; i < 2; ++i)
#pragma unroll
    for (int jj = 0; jj < 2; ++jj)
#pragma unroll
      for (int r = 0; r < 4; ++r) {
        int t = i * 16 + lg * 4 + r;
        int qw = jj * 16 + l15;
        relh_s[qw * 36 + 31 - t] = ah[i][jj][r];
      }
#pragma unroll
  for (int i = 0; i < 2; ++i)
#pragma unroll
    for (int jj = 0; jj < 4; ++jj)
#pragma unroll
      for (int r = 0; r < 4; ++r) {
        int qw = i * 16 + lg * 4 + r;
        int d = jj * 16 + l15;
        int kw = qw + 31 - d;
        if (kw >= 0 && kw < 32) relw_s[qw * 40 + kw] = f2bf(aw[i][jj][r]);
      }
  __syncthreads();

#pragma unroll
  for (int it = 0; it < 4; ++it) {
    int s = lane + it * 64;
    int row = s >> 3, c4 = (s & 7) * 4;
    *reinterpret_cast<float4*>(&relh[(bh * 1024 + qh * 32 + row) * 32 + c4]) =
        *reinterpret_cast<const float4*>(&relh_s[row * 36 + c4]);
  }
#pragma unroll
  for (int it = 0; it < 2; ++it) {
    int s = lane + it * 64;
    int row = s >> 2, ch = s & 3;
    *reinterpret_cast<int4*>(&relwb[(bh * 1024 + qh * 32 + row) * 32 + ch * 8]) =
        *reinterpret_cast<const int4*>(&relw_s[row * 40 + ch * 8]);
  }
}

// ---------------- flash attention: swapped-QK^T 32x32, exp2 domain, ROLLED
// 3-buffer counted-vmcnt pipeline (T4) — loads stay in flight across barriers ----------------
DEV_INLINE f32x16 mfma32(bf16x8 a, bf16x8 b, f32x16 c) {
  return __builtin_amdgcn_mfma_f32_32x32x16_bf16(a, b, c, 0, 0, 0);
}

DEV_INLINE bf16x8 make_pa(const float* p) {
  unsigned int W0, W1, W2, W3;
  asm("v_cvt_pk_bf16_f32 %0, %1, %2" : "=v"(W0) : "v"(p[0]), "v"(p[1]));
  asm("v_cvt_pk_bf16_f32 %0, %1, %2" : "=v"(W1) : "v"(p[2]), "v"(p[3]));
  asm("v_cvt_pk_bf16_f32 %0, %1, %2" : "=v"(W2) : "v"(p[4]), "v"(p[5]));
  asm("v_cvt_pk_bf16_f32 %0, %1, %2" : "=v"(W3) : "v"(p[6]), "v"(p[7]));
  asm("v_permlane32_swap_b32 %0, %1" : "+v"(W0), "+v"(W2));
  asm("v_permlane32_swap_b32 %0, %1" : "+v"(W1), "+v"(W3));
  union { unsigned int w[4]; bf16x8 v; } u;
  u.w[0] = W0; u.w[1] = W1; u.w[2] = W2; u.w[3] = W3;
  return u.v;
}

__global__ __launch_bounds__(128) void attn2(const unsigned short* __restrict__ kg,
                                             const unsigned short* __restrict__ vtg,
                                             const unsigned short* __restrict__ qg,
                                             const unsigned short* __restrict__ relwb,
                                             const float* __restrict__ relh,
                                             unsigned short* __restrict__ ao) {
  __shared__ unsigned short k_lin[3][64 * 64];
  __shared__ unsigned short v_lin[3][64 * 64];

  const int tid = threadIdx.x;
  const int lane = tid & 63;
  const int wv = tid >> 6;
  const int l31 = lane & 31;
  const int hi = lane >> 5;

  const int bid = blockIdx.x;
  const int swz = (bid & 7) * 96 + (bid >> 3);   // XCD-chunked: 6 bh per XCD
  const int bh = swz >> 4;
  const int qt = swz & 15;
  const int q0 = qt * 64 + wv * 32;

  bf16x8 qf[6];
  {
    const unsigned short* qrow = &qg[(bh * 1024 + q0 + l31) * 64 + hi * 8];
#pragma unroll
    for (int c = 0; c < 4; ++c)
      qf[c] = *reinterpret_cast<const bf16x8*>(&qrow[c * 16]);
    const unsigned short* wrow = &relwb[(bh * 1024 + q0 + l31) * 32 + hi * 8];
    qf[4] = *reinterpret_cast<const bf16x8*>(&wrow[0]);
    qf[5] = *reinterpret_cast<const bf16x8*>(&wrow[16]);
  }

  bf16x8 ohf0, ohf1;
  {
    int t0 = l31 - 8 * hi;
    int t1 = l31 - 16 - 8 * hi;
    union { unsigned int w[4]; bf16x8 v; } u0, u1;
#pragma unroll
    for (int w = 0; w < 4; ++w) {
      u0.w[w] = (t0 >= 0 && (t0 >> 1) == w) ? ((t0 & 1) ? 0x3F800000u : 0x3F80u) : 0u;
      u1.w[w] = (t1 >= 0 && (t1 >> 1) == w) ? ((t1 & 1) ? 0x3F800000u : 0x3F80u) : 0u;
    }
    ohf0 = u0.v; ohf1 = u1.v;
  }

  f32x16 O0, O1;
#pragma unroll
  for (int r = 0; r < 16; ++r) { O0[r] = 0.f; O1[r] = 0.f; }
  float m_r = -3.0e38f, l_r = 0.f;

  const int srow = lane >> 3;
  const int scb = (lane & 7) ^ srow;
  const int rsw = l31 & 7;

#define STAGE(KT, B)                                                                       \
  do {                                                                                     \
    _Pragma("unroll") for (int pp = 0; pp < 4; ++pp) {                                     \
      int p = wv * 4 + pp;                                                                 \
      int row = p * 8 + srow;                                                              \
      const unsigned short* gk = &kg[(bh * 1024 + (KT) * 64 + row) * 64 + scb * 8];        \
      __builtin_amdgcn_global_load_lds(                                                    \
          (const __attribute__((address_space(1))) unsigned int*)gk,                       \
          (__attribute__((address_space(3))) unsigned int*)&k_lin[B][p * 512], 16, 0, 0);  \
      const unsigned short* gv = &vtg[(bh * 64 + row) * 1024 + (KT) * 64 + scb * 8];       \
      __builtin_amdgcn_global_load_lds(                                                    \
          (const __attribute__((address_space(1))) unsigned int*)gv,                       \
          (__attribute__((address_space(3))) unsigned int*)&v_lin[B][p * 512], 16, 0, 0);  \
    }                                                                                      \
  } while (0)

  STAGE(0, 0);
  STAGE(1, 1);

  const float* rhrow = &relh[(bh * 1024 + q0 + l31) * 32];
  float2 bhv = *reinterpret_cast<const float2*>(&rhrow[0]);

  for (int kt = 0; kt < 16; ++kt) {
    const int b = kt % 3;
    // wait for tile kt only; tile kt+1's 8 loads stay in flight across the barrier
    if (kt < 15) asm volatile("s_waitcnt vmcnt(8)" ::: "memory");
    else         asm volatile("s_waitcnt vmcnt(0)" ::: "memory");
    __builtin_amdgcn_s_barrier();
    asm volatile("" ::: "memory");
    if (kt < 14) STAGE(kt + 2, (kt + 2) % 3);   // into buffer freed at kt-1

    float2 bhv_next = bhv;
    if (kt < 15) bhv_next = *reinterpret_cast<const float2*>(&rhrow[2 * (kt + 1)]);
    float bh0 = bhv.x, bh1 = bhv.y;

    f32x16 s0, s1;
#pragma unroll
    for (int r = 0; r < 16; ++r) { s0[r] = 0.f; s1[r] = 0.f; }
    {
      const unsigned short* kb0 = &k_lin[b][l31 * 64];
      const unsigned short* kb1 = &k_lin[b][(32 + l31) * 64];
      __builtin_amdgcn_s_setprio(1);
#pragma unroll
      for (int c = 0; c < 4; ++c) {
        int cb = ((2 * c + hi) ^ rsw) * 8;
        s0 = mfma32(*reinterpret_cast<const bf16x8*>(&kb0[cb]), qf[c], s0);
        s1 = mfma32(*reinterpret_cast<const bf16x8*>(&kb1[cb]), qf[c], s1);
      }
      s0 = mfma32(ohf0, qf[4], s0);
      s0 = mfma32(ohf1, qf[5], s0);
      s1 = mfma32(ohf0, qf[4], s1);
      s1 = mfma32(ohf1, qf[5], s1);
      __builtin_amdgcn_s_setprio(0);
    }

    float pm0 = s0[0], pm1 = s1[0];
#pragma unroll
    for (int r = 1; r < 16; ++r) { pm0 = fmaxf(pm0, s0[r]); pm1 = fmaxf(pm1, s1[r]); }
    float pmax = fmaxf(pm0 + bh0, pm1 + bh1);
    pmax = fmaxf(pmax, __shfl_xor(pmax, 32));

    if (!__all(pmax <= m_r + 11.5f)) {     // defer-max (log2 units): rescale is rare
      float mnew = fmaxf(m_r, pmax);
      float corr = __builtin_amdgcn_exp2f(m_r - mnew);
      m_r = mnew;
      l_r *= corr;
#pragma unroll
      for (int r = 0; r < 16; ++r) {
        int cr = ((r & 3) + 8 * (r >> 2) + 4 * hi) << 2;
        float c2 = __int_as_float(__builtin_amdgcn_ds_bpermute(cr, __float_as_int(corr)));
        O0[r] *= c2;
        O1[r] *= c2;
      }
    }

    float mb0 = m_r - bh0, mb1 = m_r - bh1;
    float p0[16], p1[16];
    float ps = 0.f;
#pragma unroll
    for (int r = 0; r < 16; ++r) { p0[r] = __builtin_amdgcn_exp2f(s0[r] - mb0); ps += p0[r]; }
#pragma unroll
    for (int r = 0; r < 16; ++r) { p1[r] = __builtin_amdgcn_exp2f(s1[r] - mb1); ps += p1[r]; }
    ps += __shfl_xor(ps, 32);
    l_r += ps;

    bf16x8 pa0 = make_pa(p0 + 0);
    bf16x8 pa1 = make_pa(p0 + 8);
    bf16x8 pa2 = make_pa(p1 + 0);
    bf16x8 pa3 = make_pa(p1 + 8);

    const unsigned short* vb0 = &v_lin[b][l31 * 64];
    const unsigned short* vb1 = &v_lin[b][(32 + l31) * 64];
    __builtin_amdgcn_s_setprio(1);
#pragma unroll
    for (int c = 0; c < 4; ++c) {
      bf16x8 pac = (c == 0) ? pa0 : (c == 1) ? pa1 : (c == 2) ? pa2 : pa3;
      int cb = ((2 * c + hi) ^ rsw) * 8;
      O0 = mfma32(pac, *reinterpret_cast<const bf16x8*>(&vb0[cb]), O0);
      O1 = mfma32(pac, *reinterpret_cast<const bf16x8*>(&vb1[cb]), O1);
    }
    __builtin_amdgcn_s_setprio(0);

    bhv = bhv_next;
  }
#undef STAGE

  float invl = 1.f / l_r;
  const int bb = bh / 12, head = bh % 12;
#pragma unroll
  for (int r = 0; r < 16; ++r) {
    int crow = (r & 3) + 8 * (r >> 2) + 4 * hi;
    float il = __int_as_float(__builtin_amdgcn_ds_bpermute(crow << 2, __float_as_int(invl)));
    int n = q0 + crow;
    unsigned short* dst = &ao[(bb * 1024 + n) * 768 + head * 64];
    dst[l31] = f2bf(O0[r] * il);
    dst[32 + l31] = f2bf(O1[r] * il);
  }
}

extern "C" void kernel_launch(void* const* d_in, const int* in_sizes, int n_in,
                              void* d_out, int out_size, void* d_ws, size_t ws_size,
                              hipStream_t stream) {
  const float* x      = (const float*)d_in[0];
  const float* qkv_w  = (const float*)d_in[1];
  const float* qkv_b  = (const float*)d_in[2];
  const float* proj_w = (const float*)d_in[3];
  const float* proj_b = (const float*)d_in[4];
  const float* rph    = (const float*)d_in[5];
  const float* rpw    = (const float*)d_in[6];
  float* out = (float*)d_out;

  char* ws = (char*)d_ws;
  unsigned short* xb    = (unsigned short*)(ws);              // 6.29MB, dead after gemm<0>
  float*          relh  = (float*)(ws);                       // reuses xb region (exactly 6.29MB)
  unsigned short* wqkv  = (unsigned short*)(ws + 6291456);
  unsigned short* wproj = (unsigned short*)(ws + 9830400);
  unsigned short* qb    = (unsigned short*)(ws + 11010048);
  unsigned short* kb    = (unsigned short*)(ws + 17301504);
  unsigned short* vb    = (unsigned short*)(ws + 23592960);   // dead after vtrans
  unsigned short* ao    = (unsigned short*)(ws + 23592960);   // reuses vb region
  unsigned short* vt    = (unsigned short*)(ws + 29884416);
  unsigned short* relwb = (unsigned short*)(ws + 36175872);   // 3.15MB, end 39.3MB

  cvt_all<<<5376, 256, 0, stream>>>(x, qkv_w, proj_w, xb, wqkv, wproj);

  gemm_bf16<0><<<dim3(18, 32), 256, 0, stream>>>(xb, wqkv, qkv_b, nullptr, qb, kb, vb);
  vtrans<<<dim3(16, 48), 256, 0, stream>>>(vb, vt);
  rel_mfma16<<<dim3(32, 48), 64, 0, stream>>>(qb, rph, rpw, relwb, relh);
  attn2<<<768, 128, 0, stream>>>(kb, vt, qb, relwb, relh, ao);
  gemm_bf16<1><<<dim3(6, 32), 256, 0, stream>>>(ao, wproj, proj_b, out, nullptr, nullptr, nullptr);
}